// Round 8
// baseline (579.022 us; speedup 1.0000x reference)
//
#include <hip/hip_runtime.h>
#include <math.h>

#define NEG_SLOPE 0.05f

__device__ __forceinline__ float leaky(float x){ return x >= 0.f ? x : NEG_SLOPE * x; }

// bf16 helpers (RNE pack, truncated-float unpack)
__device__ __forceinline__ unsigned short f2bf(float f){
    unsigned u = __float_as_uint(f);
    unsigned r = u + 0x7FFFu + ((u >> 16) & 1u);
    return (unsigned short)(r >> 16);
}
__device__ __forceinline__ float bf2f(unsigned short us){
    return __uint_as_float((unsigned)us << 16);
}

// ---------------- GEMM h = x @ Wn^T (+ bf16 copy + fused hi/hj/he epilogue + deg/ctr zeroing) ----------------
__global__ __launch_bounds__(256) void k_gemm_h(const float* __restrict__ A, const float* __restrict__ B,
        const float* __restrict__ a_node, const float* __restrict__ a_edge,
        float* __restrict__ C, unsigned short* __restrict__ Cb,
        float* __restrict__ hi, float* __restrict__ hj, float* __restrict__ he,
        int* __restrict__ deg_n, int* __restrict__ deg_o, int* __restrict__ ctr, int M){
    const int K = 128;
    __shared__ float As[K][68];
    __shared__ float Bs[K][68];
    const int m0 = blockIdx.x * 64;
    const int t = threadIdx.x;
    // fused init: zero degree arrays + counters (consumed by later kernels)
    int gt = blockIdx.x * 256 + t;
    if (gt < M){ deg_n[gt] = 0; deg_o[gt] = 0; }
    if (gt == 0){ ctr[0] = 0; ctr[1] = 0; }
    for (int i = t; i < 16 * K; i += 256){
        int d = i & 63, kq = i >> 6;
        float4 b = *(const float4*)&B[(size_t)d * K + kq * 4];
        Bs[kq*4+0][d] = b.x; Bs[kq*4+1][d] = b.y; Bs[kq*4+2][d] = b.z; Bs[kq*4+3][d] = b.w;
    }
    for (int i = t; i < 16 * K; i += 256){
        int r = i & 63, kq = i >> 6;
        int m = m0 + r;
        float4 a = make_float4(0.f, 0.f, 0.f, 0.f);
        if (m < M) a = *(const float4*)&A[(size_t)m * K + kq * 4];
        As[kq*4+0][r] = a.x; As[kq*4+1][r] = a.y; As[kq*4+2][r] = a.z; As[kq*4+3][r] = a.w;
    }
    __syncthreads();
    const int tx = t & 15, ty = t >> 4;
    float acc[4][4] = {};
    #pragma unroll 4
    for (int k = 0; k < K; k++){
        float4 a4 = *(const float4*)&As[k][ty * 4];
        float4 b4 = *(const float4*)&Bs[k][tx * 4];
        float av[4] = {a4.x, a4.y, a4.z, a4.w};
        float bv[4] = {b4.x, b4.y, b4.z, b4.w};
        #pragma unroll
        for (int r = 0; r < 4; r++)
            #pragma unroll
            for (int c = 0; c < 4; c++)
                acc[r][c] = fmaf(av[r], bv[c], acc[r][c]);
    }
    #pragma unroll
    for (int r = 0; r < 4; r++){
        int m = m0 + ty * 4 + r;
        if (m < M){
            float4 o = make_float4(acc[r][0], acc[r][1], acc[r][2], acc[r][3]);
            *(float4*)&C[(size_t)m * 64 + tx * 4] = o;
            uint2 u;
            u.x = (unsigned)f2bf(o.x) | ((unsigned)f2bf(o.y) << 16);
            u.y = (unsigned)f2bf(o.z) | ((unsigned)f2bf(o.w) << 16);
            *(uint2*)&Cb[(size_t)m * 64 + tx * 4] = u;
        }
    }
    // fused per-row scalars: hi = h.a_node[:64], hj = h.a_node[64:], he = h.a_edge[:64]
    float4 an1 = *(const float4*)&a_node[tx * 4];
    float4 an2 = *(const float4*)&a_node[64 + tx * 4];
    float4 ae1 = *(const float4*)&a_edge[tx * 4];
    float p1[4], p2[4], p3[4];
    #pragma unroll
    for (int r = 0; r < 4; r++){
        p1[r] = acc[r][0]*an1.x + acc[r][1]*an1.y + acc[r][2]*an1.z + acc[r][3]*an1.w;
        p2[r] = acc[r][0]*an2.x + acc[r][1]*an2.y + acc[r][2]*an2.z + acc[r][3]*an2.w;
        p3[r] = acc[r][0]*ae1.x + acc[r][1]*ae1.y + acc[r][2]*ae1.z + acc[r][3]*ae1.w;
    }
    #pragma unroll
    for (int m = 1; m < 16; m <<= 1){
        #pragma unroll
        for (int r = 0; r < 4; r++){
            p1[r] += __shfl_xor(p1[r], m);
            p2[r] += __shfl_xor(p2[r], m);
            p3[r] += __shfl_xor(p3[r], m);
        }
    }
    if (tx == 0){
        #pragma unroll
        for (int r = 0; r < 4; r++){
            int m = m0 + ty * 4 + r;
            if (m < M){ hi[m] = p1[r]; hj[m] = p2[r]; he[m] = p3[r]; }
        }
    }
}

// ---------------- coalesced ea stream: ge + bf16 copy + fused degree count; vv computed in-block ----------------
__global__ __launch_bounds__(256) void k_ge2(const float* __restrict__ ea, const int* __restrict__ idx,
        const float* __restrict__ We, const float* __restrict__ a_edge,
        float* __restrict__ ge, unsigned short* __restrict__ eab,
        int* __restrict__ deg_n, int* __restrict__ deg_o, int E){
    __shared__ float vvs[64];
    int t = threadIdx.x;
    if (t < 64){
        float s = 0.f;
        for (int d = 0; d < 64; d++) s = fmaf(We[d * 64 + t], a_edge[64 + d], s);
        vvs[t] = s;
    }
    __syncthreads();
    int l = t & 63;
    int gw = (blockIdx.x * 256 + t) >> 6;   // global wave id
    int nw = (gridDim.x * 256) >> 6;
    int seg = l & 15, rl = l >> 4;
    float4 v4 = *(const float4*)&vvs[seg * 4];
    for (int r0 = gw * 4; r0 < E; r0 += nw * 4){
        int row = r0 + rl;
        if (row < E){
            float4 a = *(const float4*)&ea[(size_t)row * 64 + seg * 4];
            float s = a.x*v4.x + a.y*v4.y + a.z*v4.z + a.w*v4.w;
            uint2 u;
            u.x = (unsigned)f2bf(a.x) | ((unsigned)f2bf(a.y) << 16);
            u.y = (unsigned)f2bf(a.z) | ((unsigned)f2bf(a.w) << 16);
            *(uint2*)&eab[(size_t)row * 64 + seg * 4] = u;
            #pragma unroll
            for (int m = 1; m < 16; m <<= 1) s += __shfl_xor(s, m);
            if (seg == 0){
                ge[row] = s;
                int i0 = idx[row], i1 = idx[E + row];
                atomicAdd(&deg_n[i0], 1);
                atomicAdd(&deg_o[i1], 1);
            }
        }
    }
}

// ---------------- offset assignment: wave shfl-scan + one atomic per wave (ranges disjoint, order free) ----------------
__global__ __launch_bounds__(256) void k_off(const int* __restrict__ deg_n, const int* __restrict__ deg_o,
        int* __restrict__ deg_e,
        int* __restrict__ off_n, int* __restrict__ cur_n,
        int* __restrict__ off_e, int* __restrict__ cur_e,
        int* __restrict__ ctr, int N){
    int i = blockIdx.x * 256 + threadIdx.x;
    int lane = threadIdx.x & 63;
    int dn = 0, de = 0;
    if (i < N){
        dn = deg_n[i];
        de = dn + deg_o[i];
    }
    int pn = dn, pe = de;   // inclusive wave scan
    #pragma unroll
    for (int d = 1; d < 64; d <<= 1){
        int on = __shfl_up(pn, d), oe = __shfl_up(pe, d);
        if (lane >= d){ pn += on; pe += oe; }
    }
    int base_n = 0, base_e = 0;
    if (lane == 63){
        base_n = atomicAdd(&ctr[0], pn);
        base_e = atomicAdd(&ctr[1], pe);
    }
    base_n = __shfl(base_n, 63);
    base_e = __shfl(base_e, 63);
    if (i < N){
        int on = base_n + pn - dn;   // exclusive within wave
        int oe = base_e + pe - de;
        off_n[i] = on; cur_n[i] = on;
        off_e[i] = oe; cur_e[i] = oe;
        deg_e[i] = de;
    }
}

// ---------------- XCD-partitioned fill; records carry the FINAL attention weight ----------------
// node record: {j, exp(leaky(hi[i0]+hj[j]))}; edge record: {k, exp(leaky(he[side]+ge[k]))}
__global__ __launch_bounds__(256) void k_fill(const int* __restrict__ idx,
        const float* __restrict__ hi, const float* __restrict__ hj,
        const float* __restrict__ he, const float* __restrict__ ge,
        int* __restrict__ cur_n, int* __restrict__ cur_e,
        int2* __restrict__ adj_n, int2* __restrict__ adj_e, int E, int N){
    int g = blockIdx.x & 7;
    int lo = (int)(((long long)g * N) >> 3), hi_b = (int)(((long long)(g + 1) * N) >> 3);
    int nblk = gridDim.x >> 3;
    int start = ((blockIdx.x >> 3) * 256) + threadIdx.x;
    int stride = nblk * 256;
    for (int k = start; k < E; k += stride){
        int i0 = idx[k], i1 = idx[E + k];
        bool t0 = (i0 >= lo && i0 < hi_b), t1 = (i1 >= lo && i1 < hi_b);
        if (t0 | t1){
            float gek = ge[k];
            if (t0){
                float wn  = __expf(leaky(hi[i0] + hj[i1]));
                float we0 = __expf(leaky(he[i0] + gek));
                adj_n[atomicAdd(&cur_n[i0], 1)] = make_int2(i1, __float_as_int(wn));
                adj_e[atomicAdd(&cur_e[i0], 1)] = make_int2(k, __float_as_int(we0));
            }
            if (t1){
                float we1 = __expf(leaky(he[i1] + gek));
                adj_e[atomicAdd(&cur_e[i1], 1)] = make_int2(k, __float_as_int(we1));
            }
        }
    }
}

// ---------------- merged output kernel: 16 records/iter, weights pre-baked in records ----------------
// blocks [0, nb_node): node branch -> out[:, :64]
// blocks [nb_node, 2*nb_node): edge branch + fused We matvec -> out[:, 64:]
__global__ __launch_bounds__(256) void k_out(const float* __restrict__ h,
        const unsigned short* __restrict__ hb, const unsigned short* __restrict__ eab,
        const float* __restrict__ hi, const float* __restrict__ hj,
        const float* __restrict__ We,
        const int* __restrict__ off_n, const int* __restrict__ deg_n, const int2* __restrict__ adj_n,
        const int* __restrict__ off_e, const int* __restrict__ deg_e, const int2* __restrict__ adj_e,
        float* __restrict__ out, int N, int nb_node){
    __shared__ float WeT[64][65];
    __shared__ float valS[4][64];
    const int lane = threadIdx.x & 63;
    const int w = threadIdx.x >> 6;
    const int rl = lane >> 4, seg = lane & 15;

    if (blockIdx.x < nb_node){
        // ---------- node branch ----------
        int i = (blockIdx.x * 256 + (int)threadIdx.x) >> 6;
        if (i >= N) return;
        int cnt = deg_n[i];
        int p = off_n[i];
        int e = p + cnt;
        float a0 = 0.f, a1 = 0.f, a2 = 0.f, a3 = 0.f, sp = 0.f;
        for (; p + 16 <= e; p += 16){
            int2 q0 = adj_n[p + rl];
            int2 q1 = adj_n[p + 4 + rl];
            int2 q2 = adj_n[p + 8 + rl];
            int2 q3 = adj_n[p + 12 + rl];
            uint2 u0 = *(const uint2*)&hb[(size_t)q0.x * 64 + seg * 4];
            uint2 u1 = *(const uint2*)&hb[(size_t)q1.x * 64 + seg * 4];
            uint2 u2 = *(const uint2*)&hb[(size_t)q2.x * 64 + seg * 4];
            uint2 u3 = *(const uint2*)&hb[(size_t)q3.x * 64 + seg * 4];
            float w0 = __int_as_float(q0.y);
            float w1 = __int_as_float(q1.y);
            float w2 = __int_as_float(q2.y);
            float w3 = __int_as_float(q3.y);
            a0 = fmaf(w0, bf2f((unsigned short)u0.x), a0);
            a1 = fmaf(w0, bf2f((unsigned short)(u0.x >> 16)), a1);
            a2 = fmaf(w0, bf2f((unsigned short)u0.y), a2);
            a3 = fmaf(w0, bf2f((unsigned short)(u0.y >> 16)), a3);
            a0 = fmaf(w1, bf2f((unsigned short)u1.x), a0);
            a1 = fmaf(w1, bf2f((unsigned short)(u1.x >> 16)), a1);
            a2 = fmaf(w1, bf2f((unsigned short)u1.y), a2);
            a3 = fmaf(w1, bf2f((unsigned short)(u1.y >> 16)), a3);
            a0 = fmaf(w2, bf2f((unsigned short)u2.x), a0);
            a1 = fmaf(w2, bf2f((unsigned short)(u2.x >> 16)), a1);
            a2 = fmaf(w2, bf2f((unsigned short)u2.y), a2);
            a3 = fmaf(w2, bf2f((unsigned short)(u2.y >> 16)), a3);
            a0 = fmaf(w3, bf2f((unsigned short)u3.x), a0);
            a1 = fmaf(w3, bf2f((unsigned short)(u3.x >> 16)), a1);
            a2 = fmaf(w3, bf2f((unsigned short)u3.y), a2);
            a3 = fmaf(w3, bf2f((unsigned short)(u3.y >> 16)), a3);
            sp += (w0 + w1) + (w2 + w3);
        }
        if (p + 8 <= e){
            int2 q0 = adj_n[p + rl];
            int2 q1 = adj_n[p + 4 + rl];
            uint2 u0 = *(const uint2*)&hb[(size_t)q0.x * 64 + seg * 4];
            uint2 u1 = *(const uint2*)&hb[(size_t)q1.x * 64 + seg * 4];
            float w0 = __int_as_float(q0.y);
            float w1 = __int_as_float(q1.y);
            a0 = fmaf(w0, bf2f((unsigned short)u0.x), a0);
            a1 = fmaf(w0, bf2f((unsigned short)(u0.x >> 16)), a1);
            a2 = fmaf(w0, bf2f((unsigned short)u0.y), a2);
            a3 = fmaf(w0, bf2f((unsigned short)(u0.y >> 16)), a3);
            a0 = fmaf(w1, bf2f((unsigned short)u1.x), a0);
            a1 = fmaf(w1, bf2f((unsigned short)(u1.x >> 16)), a1);
            a2 = fmaf(w1, bf2f((unsigned short)u1.y), a2);
            a3 = fmaf(w1, bf2f((unsigned short)(u1.y >> 16)), a3);
            sp += w0 + w1;
            p += 8;
        }
        if (p + 4 <= e){
            int2 q0 = adj_n[p + rl];
            uint2 u0 = *(const uint2*)&hb[(size_t)q0.x * 64 + seg * 4];
            float w0 = __int_as_float(q0.y);
            a0 = fmaf(w0, bf2f((unsigned short)u0.x), a0);
            a1 = fmaf(w0, bf2f((unsigned short)(u0.x >> 16)), a1);
            a2 = fmaf(w0, bf2f((unsigned short)u0.y), a2);
            a3 = fmaf(w0, bf2f((unsigned short)(u0.y >> 16)), a3);
            sp += w0;
            p += 4;
        }
        int rem = e - p;
        if (rl < rem){
            int2 q0 = adj_n[p + rl];
            uint2 u0 = *(const uint2*)&hb[(size_t)q0.x * 64 + seg * 4];
            float w0 = __int_as_float(q0.y);
            a0 = fmaf(w0, bf2f((unsigned short)u0.x), a0);
            a1 = fmaf(w0, bf2f((unsigned short)(u0.x >> 16)), a1);
            a2 = fmaf(w0, bf2f((unsigned short)u0.y), a2);
            a3 = fmaf(w0, bf2f((unsigned short)(u0.y >> 16)), a3);
            sp += w0;
        }
        a0 += __shfl_xor(a0, 16); a0 += __shfl_xor(a0, 32);
        a1 += __shfl_xor(a1, 16); a1 += __shfl_xor(a1, 32);
        a2 += __shfl_xor(a2, 16); a2 += __shfl_xor(a2, 32);
        a3 += __shfl_xor(a3, 16); a3 += __shfl_xor(a3, 32);
        sp += __shfl_xor(sp, 16); sp += __shfl_xor(sp, 32);
        if (rl == 0){
            float4 h4 = *(const float4*)&h[(size_t)i * 64 + seg * 4];
            float wself = __expf(leaky(hi[i] + hj[i]));
            float s = sp + wself;
            float inv = 1.f / (s * (float)(cnt + 1));
            float4 o;
            o.x = leaky(fmaf(wself, h4.x, a0) * inv);
            o.y = leaky(fmaf(wself, h4.y, a1) * inv);
            o.z = leaky(fmaf(wself, h4.z, a2) * inv);
            o.w = leaky(fmaf(wself, h4.w, a3) * inv);
            *(float4*)&out[(size_t)i * 128 + seg * 4] = o;
        }
    } else {
        // ---------- edge branch ----------
        for (int t2 = threadIdx.x; t2 < 1024; t2 += 256){
            int d = t2 >> 4, c0 = (t2 & 15) * 4;
            float4 v = *(const float4*)&We[d * 64 + c0];
            WeT[c0+0][d] = v.x; WeT[c0+1][d] = v.y; WeT[c0+2][d] = v.z; WeT[c0+3][d] = v.w;
        }
        int i = ((blockIdx.x - nb_node) * 256 + (int)threadIdx.x) >> 6;
        const int iok = (i < N);
        float v0 = 0.f, v1 = 0.f, v2 = 0.f, v3 = 0.f;
        if (iok){
            int cnt = deg_e[i];
            int p = off_e[i];
            int e = p + cnt;
            float a0 = 0.f, a1 = 0.f, a2 = 0.f, a3 = 0.f, sp = 0.f;
            for (; p + 16 <= e; p += 16){
                int2 q0 = adj_e[p + rl];
                int2 q1 = adj_e[p + 4 + rl];
                int2 q2 = adj_e[p + 8 + rl];
                int2 q3 = adj_e[p + 12 + rl];
                uint2 u0 = *(const uint2*)&eab[(size_t)q0.x * 64 + seg * 4];
                uint2 u1 = *(const uint2*)&eab[(size_t)q1.x * 64 + seg * 4];
                uint2 u2 = *(const uint2*)&eab[(size_t)q2.x * 64 + seg * 4];
                uint2 u3 = *(const uint2*)&eab[(size_t)q3.x * 64 + seg * 4];
                float w0 = __int_as_float(q0.y);
                float w1 = __int_as_float(q1.y);
                float w2 = __int_as_float(q2.y);
                float w3 = __int_as_float(q3.y);
                a0 = fmaf(w0, bf2f((unsigned short)u0.x), a0);
                a1 = fmaf(w0, bf2f((unsigned short)(u0.x >> 16)), a1);
                a2 = fmaf(w0, bf2f((unsigned short)u0.y), a2);
                a3 = fmaf(w0, bf2f((unsigned short)(u0.y >> 16)), a3);
                a0 = fmaf(w1, bf2f((unsigned short)u1.x), a0);
                a1 = fmaf(w1, bf2f((unsigned short)(u1.x >> 16)), a1);
                a2 = fmaf(w1, bf2f((unsigned short)u1.y), a2);
                a3 = fmaf(w1, bf2f((unsigned short)(u1.y >> 16)), a3);
                a0 = fmaf(w2, bf2f((unsigned short)u2.x), a0);
                a1 = fmaf(w2, bf2f((unsigned short)(u2.x >> 16)), a1);
                a2 = fmaf(w2, bf2f((unsigned short)u2.y), a2);
                a3 = fmaf(w2, bf2f((unsigned short)(u2.y >> 16)), a3);
                a0 = fmaf(w3, bf2f((unsigned short)u3.x), a0);
                a1 = fmaf(w3, bf2f((unsigned short)(u3.x >> 16)), a1);
                a2 = fmaf(w3, bf2f((unsigned short)u3.y), a2);
                a3 = fmaf(w3, bf2f((unsigned short)(u3.y >> 16)), a3);
                sp += (w0 + w1) + (w2 + w3);
            }
            if (p + 8 <= e){
                int2 q0 = adj_e[p + rl];
                int2 q1 = adj_e[p + 4 + rl];
                uint2 u0 = *(const uint2*)&eab[(size_t)q0.x * 64 + seg * 4];
                uint2 u1 = *(const uint2*)&eab[(size_t)q1.x * 64 + seg * 4];
                float w0 = __int_as_float(q0.y);
                float w1 = __int_as_float(q1.y);
                a0 = fmaf(w0, bf2f((unsigned short)u0.x), a0);
                a1 = fmaf(w0, bf2f((unsigned short)(u0.x >> 16)), a1);
                a2 = fmaf(w0, bf2f((unsigned short)u0.y), a2);
                a3 = fmaf(w0, bf2f((unsigned short)(u0.y >> 16)), a3);
                a0 = fmaf(w1, bf2f((unsigned short)u1.x), a0);
                a1 = fmaf(w1, bf2f((unsigned short)(u1.x >> 16)), a1);
                a2 = fmaf(w1, bf2f((unsigned short)u1.y), a2);
                a3 = fmaf(w1, bf2f((unsigned short)(u1.y >> 16)), a3);
                sp += w0 + w1;
                p += 8;
            }
            if (p + 4 <= e){
                int2 q0 = adj_e[p + rl];
                uint2 u0 = *(const uint2*)&eab[(size_t)q0.x * 64 + seg * 4];
                float w0 = __int_as_float(q0.y);
                a0 = fmaf(w0, bf2f((unsigned short)u0.x), a0);
                a1 = fmaf(w0, bf2f((unsigned short)(u0.x >> 16)), a1);
                a2 = fmaf(w0, bf2f((unsigned short)u0.y), a2);
                a3 = fmaf(w0, bf2f((unsigned short)(u0.y >> 16)), a3);
                sp += w0;
                p += 4;
            }
            int rem = e - p;
            if (rl < rem){
                int2 q0 = adj_e[p + rl];
                uint2 u0 = *(const uint2*)&eab[(size_t)q0.x * 64 + seg * 4];
                float w0 = __int_as_float(q0.y);
                a0 = fmaf(w0, bf2f((unsigned short)u0.x), a0);
                a1 = fmaf(w0, bf2f((unsigned short)(u0.x >> 16)), a1);
                a2 = fmaf(w0, bf2f((unsigned short)u0.y), a2);
                a3 = fmaf(w0, bf2f((unsigned short)(u0.y >> 16)), a3);
                sp += w0;
            }
            a0 += __shfl_xor(a0, 16); a0 += __shfl_xor(a0, 32);
            a1 += __shfl_xor(a1, 16); a1 += __shfl_xor(a1, 32);
            a2 += __shfl_xor(a2, 16); a2 += __shfl_xor(a2, 32);
            a3 += __shfl_xor(a3, 16); a3 += __shfl_xor(a3, 32);
            sp += __shfl_xor(sp, 16); sp += __shfl_xor(sp, 32);
            if (cnt > 0){
                float inv = 1.f / (sp * (float)cnt);
                v0 = a0 * inv; v1 = a1 * inv; v2 = a2 * inv; v3 = a3 * inv;
            }
        }
        __syncthreads();                 // WeT ready
        if (rl == 0) *(float4*)&valS[w][seg * 4] = make_float4(v0, v1, v2, v3);
        __syncthreads();                 // valS visible
        if (iok){
            float acc2 = 0.f;
            #pragma unroll
            for (int c4 = 0; c4 < 16; c4++){
                float4 vb = *(const float4*)&valS[w][c4 * 4];
                acc2 = fmaf(vb.x, WeT[c4*4+0][lane], acc2);
                acc2 = fmaf(vb.y, WeT[c4*4+1][lane], acc2);
                acc2 = fmaf(vb.z, WeT[c4*4+2][lane], acc2);
                acc2 = fmaf(vb.w, WeT[c4*4+3][lane], acc2);
            }
            out[(size_t)i * 128 + 64 + lane] = leaky(acc2);
        }
    }
}

extern "C" void kernel_launch(void* const* d_in, const int* in_sizes, int n_in,
                              void* d_out, int out_size, void* d_ws, size_t ws_size,
                              hipStream_t stream){
    const float* x      = (const float*)d_in[0];
    const float* ea     = (const float*)d_in[1];
    const int*   idx    = (const int*)  d_in[2];
    const float* Wn     = (const float*)d_in[3];
    const float* We     = (const float*)d_in[4];
    const float* a_node = (const float*)d_in[5];
    const float* a_edge = (const float*)d_in[6];
    float* out = (float*)d_out;

    const int N = in_sizes[0] / 128;   // 50000
    const int E = in_sizes[1] / 64;    // 800000

    float* p = (float*)d_ws;
    float* h      = p; p += (size_t)N * 64;
    float* hi     = p; p += N;
    float* hj     = p; p += N;
    float* he     = p; p += N;
    float* ge     = p; p += E;
    unsigned short* hb  = (unsigned short*)p; p += (size_t)N * 32;   // bf16 h
    unsigned short* eab = (unsigned short*)p; p += (size_t)E * 32;   // bf16 ea
    int* deg_n = (int*)p; p += N;
    int* deg_o = (int*)p; p += N;
    int* deg_e = (int*)p; p += N;
    int* off_n = (int*)p; p += N;
    int* off_e = (int*)p; p += N;
    int* cur_n = (int*)p; p += N;
    int* cur_e = (int*)p; p += N;
    int* ctr   = (int*)p; p += 4;
    int2* adj_n = (int2*)p; p += (size_t)2 * E;
    int2* adj_e = (int2*)p; p += (size_t)4 * E;

    const int nb = (N + 3) / 4;

    k_gemm_h<<<(N + 63) / 64, 256, 0, stream>>>(x, Wn, a_node, a_edge, h, hb, hi, hj, he,
                                                deg_n, deg_o, ctr, N);
    k_ge2<<<2048, 256, 0, stream>>>(ea, idx, We, a_edge, ge, eab, deg_n, deg_o, E);
    k_off<<<(N + 255) / 256, 256, 0, stream>>>(deg_n, deg_o, deg_e, off_n, cur_n, off_e, cur_e, ctr, N);
    k_fill<<<1024, 256, 0, stream>>>(idx, hi, hj, he, ge, cur_n, cur_e, adj_n, adj_e, E, N);
    k_out<<<2 * nb, 256, 0, stream>>>(h, hb, eab, hi, hj, We,
                                      off_n, deg_n, adj_n, off_e, deg_e, adj_e, out, N, nb);
}